// Round 18
// baseline (376.516 us; speedup 1.0000x reference)
//
#include <hip/hip_runtime.h>
#include <math.h>

typedef long long i64;
typedef unsigned long long u64;

#define GWD 1024
#define GMSK 1023
#define GSH 10

__device__ __forceinline__ int xcd_band(int b, int nb) {
  return (b & 7) * (nb >> 3) + (b >> 3);
}

__device__ __forceinline__ int deg_of(int m) {
  int xx = m & GMSK, yy = m >> GSH;
  return (xx > 0) + (xx < GMSK) + (yy > 0) + (yy < GMSK);
}

// ============ A: level-1 matching, fully static neighbor slots ============
__global__ __launch_bounds__(256)
void kA_match1(const float* __restrict__ x, int* __restrict__ partner1, int n) {
#pragma clang fp contract(off)
  int m = xcd_band(blockIdx.x, gridDim.x) * 256 + threadIdx.x;
  if (m >= n) return;
  int xx = m & GMSK, yy = m >> GSH;
  bool vW = xx > 0, vE = xx < GMSK, vN = yy > 0, vS = yy < GMSK;
  int cnt = (int)vW + (int)vE + (int)vN + (int)vS;
  float invi = 1.0f / (float)cnt;
  float xm0 = x[(i64)m * 5];
  float best = -INFINITY;
  int pr = n;
#define NB1(valid, J)                                                  \
  if (valid) {                                                         \
    int j = (J);                                                       \
    float a0 = x[(i64)j * 5];                                          \
    float w = fabsf(xm0 - a0) * (invi + 1.0f / (float)deg_of(j));      \
    if (w > best) { best = w; pr = j; }                                \
  }
  NB1(vN, m - GWD)
  NB1(vW, m - 1)
  NB1(vE, m + 1)
  NB1(vS, m + GWD)
#undef NB1
  partner1[m] = pr;
}

// ============ B: c1 + mem1 (all nodes) + head-only xp / pd.xy ============
__device__ __forceinline__ void conv1_static(const float* __restrict__ x, int m,
                                             const float* w1, const float* w1r,
                                             const float* b1, float (&out)[16]) {
  int xx = m & GMSK, yy = m >> GSH;
  bool vW = xx > 0, vE = xx < GMSK, vN = yy > 0, vS = yy < GMSK;
  int cnt = (int)vW + (int)vE + (int)vN + (int)vS;
  float s0 = 0.f, s1 = 0.f, s2 = 0.f, s3 = 0.f, s4 = 0.f;
#define ACC1(valid, J)                                     \
  if (valid) {                                             \
    const float* xj = x + (i64)(J) * 5;                    \
    s0 += xj[0]; s1 += xj[1]; s2 += xj[2];                 \
    s3 += xj[3]; s4 += xj[4];                              \
  }
  ACC1(vN, m - GWD)
  ACC1(vW, m - 1)
  ACC1(vE, m + 1)
  ACC1(vS, m + GWD)
#undef ACC1
  const float* xm = x + (i64)m * 5;
  float m0 = xm[0], m1 = xm[1], m2 = xm[2], m3 = xm[3], m4 = xm[4];
  float cf = (float)cnt;
#pragma unroll
  for (int f = 0; f < 16; ++f) {
    float a  = s0 * w1[f] + s1 * w1[16 + f] + s2 * w1[32 + f] + s3 * w1[48 + f] + s4 * w1[64 + f];
    float rt = m0 * w1r[f] + m1 * w1r[16 + f] + m2 * w1r[32 + f] + m3 * w1r[48 + f] + m4 * w1r[64 + f];
    out[f] = fmaxf(a / cf + rt + b1[f], 0.0f);
  }
}

__global__ __launch_bounds__(256)
void kB_pool1(const float* __restrict__ x, const float* __restrict__ pos,
              const int* __restrict__ partner1,
              const float* __restrict__ W1, const float* __restrict__ W1r,
              const float* __restrict__ b1,
              int* __restrict__ c1, int* __restrict__ mem1,
              float* __restrict__ xp, float* __restrict__ pd, int n) {
  __shared__ float w1s[80], w1rs[80], b1s[16];
  for (int t = threadIdx.x; t < 80; t += 256) { w1s[t] = W1[t]; w1rs[t] = W1r[t]; }
  if (threadIdx.x < 16) b1s[threadIdx.x] = b1[threadIdx.x];
  __syncthreads();
  int m = xcd_band(blockIdx.x, gridDim.x) * 256 + threadIdx.x;
  if (m >= n) return;
  int p = partner1[m];
  bool mut = (partner1[p] == m);
  int head = mut ? min(m, p) : m;
  c1[m] = head;
  mem1[m] = mut ? p : m;
  if (head != m) return;

  float px = pos[(i64)m * 2], py = pos[(i64)m * 2 + 1];
  if (mut) {
    px = (px + pos[(i64)p * 2]) * 0.5f;
    py = (py + pos[(i64)p * 2 + 1]) * 0.5f;
  }
  pd[(i64)m * 4]     = px;
  pd[(i64)m * 4 + 1] = py;

  float v[16];
  conv1_static(x, m, w1s, w1rs, b1s, v);
  if (mut) {
    float u[16];
    conv1_static(x, p, w1s, w1rs, b1s, u);
#pragma unroll
    for (int f = 0; f < 16; ++f) v[f] = fmaxf(v[f], u[f]);
  }
#pragma unroll
  for (int f = 0; f < 16; ++f) xp[(i64)m * 16 + f] = v[f];
}

// ============ C: coarse inverse-degree into pd.z (heads only) ============
__device__ __forceinline__ int dcount(const int* __restrict__ c1, int q, int cq) {
  int xx = q & GMSK, yy = q >> GSH;
  int d = 0;
  if (yy > 0    && c1[q - GWD] != cq) ++d;
  if (xx > 0    && c1[q - 1]   != cq) ++d;
  if (xx < GMSK && c1[q + 1]   != cq) ++d;
  if (yy < GMSK && c1[q + GWD] != cq) ++d;
  return d;
}

__global__ __launch_bounds__(256)
void kC_deg2(const int* __restrict__ mem1, const int* __restrict__ c1,
             float* __restrict__ pd, int n) {
  int m = xcd_band(blockIdx.x, gridDim.x) * 256 + threadIdx.x;
  if (m >= n) return;
  if (c1[m] != m) return;
  int p = mem1[m];
  bool mut = (p != m);
  int d = dcount(c1, m, m);
  if (mut) d += dcount(c1, p, m);
  pd[(i64)m * 4 + 2] = (d > 0) ? 1.0f / (float)d : 0.0f;
}

// ============ D: level-2 matching (heads only), packed pd float4 reads ============
__global__ __launch_bounds__(256)
void kD_match2(const int* __restrict__ mem1, const int* __restrict__ c1,
               const float* __restrict__ pd, int* __restrict__ partner2, int n) {
#pragma clang fp contract(off)
  int i = xcd_band(blockIdx.x, gridDim.x) * 256 + threadIdx.x;
  if (i >= n) return;
  if (c1[i] != i) return;
  int p = mem1[i];
  bool mut = (p != i);
  float4 mine = *(const float4*)(pd + (i64)i * 4);
  float pix = mine.x, piy = mine.y, invi = mine.z;
  float best = -INFINITY;
  int bc = n;
#define NB2(valid, J)                                                   \
  if (valid) {                                                          \
    int j = (J);                                                        \
    int cu = c1[j];                                                     \
    if (cu != i) {                                                      \
      float4 u = *(const float4*)(pd + (i64)cu * 4);                    \
      float dx = pix - u.x;                                             \
      float dy = piy - u.y;                                             \
      float attr = sqrtf((dx * dx + dy * dy) + 1e-12f);                 \
      float w = attr * (invi + u.z);                                    \
      if (w > best) { best = w; bc = cu; }                              \
      else if (w == best && cu < bc) bc = cu;                           \
    }                                                                   \
  }
  {
    int xx = i & GMSK, yy = i >> GSH;
    NB2(yy > 0, i - GWD)
    NB2(xx > 0, i - 1)
    NB2(xx < GMSK, i + 1)
    NB2(yy < GMSK, i + GWD)
  }
  if (mut) {
    int qx = p & GMSK, qy = p >> GSH;
    NB2(qy > 0, p - GWD)
    NB2(qx > 0, p - 1)
    NB2(qx < GMSK, p + 1)
    NB2(qy < GMSK, p + GWD)
  }
#undef NB2
  partner2[i] = (bc >= n) ? i : bc;
}

// ============ P: deterministic compaction of level-2 heads -> int2 descriptors ============
__device__ __forceinline__ bool l2head(const int* __restrict__ c1,
                                       const int* __restrict__ partner2, int i, int n) {
  if (i >= n || c1[i] != i) return false;
  int p2 = partner2[i];
  bool mut2 = (p2 != i) && (partner2[p2] == i);
  return !(mut2 && p2 < i);
}

__global__ __launch_bounds__(256)
void kP_count(const int* __restrict__ c1, const int* __restrict__ partner2,
              int* __restrict__ blockCounts, int n) {
  int w = xcd_band(blockIdx.x, gridDim.x);
  int i = w * 256 + threadIdx.x;
  bool a = l2head(c1, partner2, i, n);
  u64 b = __ballot(a);
  __shared__ int wc4[4];
  int lane = threadIdx.x & 63, wv = threadIdx.x >> 6;
  if (lane == 0) wc4[wv] = __popcll(b);
  __syncthreads();
  if (threadIdx.x == 0) blockCounts[w] = wc4[0] + wc4[1] + wc4[2] + wc4[3];
}

__global__ __launch_bounds__(256)
void kP_scan(const int* __restrict__ blockCounts, int* __restrict__ blockOffsets,
             int* __restrict__ countBuf, int nblk,
             const float* __restrict__ W2, const float* __restrict__ W2r,
             float* __restrict__ W2T, float* __restrict__ W2rT) {
  int t = threadIdx.x;
  for (int e = t; e < 512; e += 256) {
    int k = e >> 5, f = e & 31;
    W2T[f * 16 + k]  = W2[e];
    W2rT[f * 16 + k] = W2r[e];
  }
  __shared__ int tsum[256];
  __shared__ int toff[256];
  int per = (nblk + 255) / 256;
  int base = t * per;
  int s = 0;
  for (int k = 0; k < per; ++k) { int q = base + k; if (q < nblk) s += blockCounts[q]; }
  tsum[t] = s;
  __syncthreads();
  if (t == 0) {
    int a = 0;
    for (int k = 0; k < 256; ++k) { toff[k] = a; a += tsum[k]; }
    *countBuf = a;
  }
  __syncthreads();
  int off = toff[t];
  for (int k = 0; k < per; ++k) {
    int q = base + k;
    if (q < nblk) { blockOffsets[q] = off; off += blockCounts[q]; }
  }
}

__global__ __launch_bounds__(256)
void kP_write(const int* __restrict__ c1, const int* __restrict__ partner2,
              const int* __restrict__ blockOffsets, int2* __restrict__ Ldesc, int n) {
  int w = xcd_band(blockIdx.x, gridDim.x);
  int i = w * 256 + threadIdx.x;
  bool a = l2head(c1, partner2, i, n);
  u64 b = __ballot(a);
  int lane = threadIdx.x & 63, wv = threadIdx.x >> 6;
  __shared__ int woff[4];
  if (lane == 0) woff[wv] = __popcll(b);
  __syncthreads();
  int pre = 0;
  for (int k = 0; k < wv; ++k) pre += woff[k];
  int rank = __popcll(b & ((lane == 0) ? 0ull : ((1ull << lane) - 1ull)));
  if (a) {
    int p2 = partner2[i];
    bool mut2 = (p2 != i) && (partner2[p2] == i);
    Ldesc[blockOffsets[w] + pre + rank] = make_int2(i, mut2 ? p2 : i);
  }
}

// ============ E12: conv2 + pool2 — LDS reduction + 4-way ILP feature sums ============
#define DECL16(P) \
  float P##0=0.f,P##1=0.f,P##2=0.f,P##3=0.f,P##4=0.f,P##5=0.f,P##6=0.f,P##7=0.f, \
        P##8=0.f,P##9=0.f,P##10=0.f,P##11=0.f,P##12=0.f,P##13=0.f,P##14=0.f,P##15=0.f

#define LOAD16(P, ptr) do { const float* _q=(ptr); \
  P##0=_q[0]; P##1=_q[1]; P##2=_q[2]; P##3=_q[3]; P##4=_q[4]; P##5=_q[5]; P##6=_q[6]; P##7=_q[7]; \
  P##8=_q[8]; P##9=_q[9]; P##10=_q[10]; P##11=_q[11]; P##12=_q[12]; P##13=_q[13]; P##14=_q[14]; P##15=_q[15]; } while(0)

#define ADD16(P, ptr) do { const float* _q=(ptr); \
  P##0+=_q[0]; P##1+=_q[1]; P##2+=_q[2]; P##3+=_q[3]; P##4+=_q[4]; P##5+=_q[5]; P##6+=_q[6]; P##7+=_q[7]; \
  P##8+=_q[8]; P##9+=_q[9]; P##10+=_q[10]; P##11+=_q[11]; P##12+=_q[12]; P##13+=_q[13]; P##14+=_q[14]; P##15+=_q[15]; } while(0)

#define MUL16(P, v) do { float _v=(v); \
  P##0*=_v; P##1*=_v; P##2*=_v; P##3*=_v; P##4*=_v; P##5*=_v; P##6*=_v; P##7*=_v; \
  P##8*=_v; P##9*=_v; P##10*=_v; P##11*=_v; P##12*=_v; P##13*=_v; P##14*=_v; P##15*=_v; } while(0)

#define GATHER_MEMBER(P, CNT, m, cid) do {                                      \
  int _m = (m); int _mx = _m & GMSK, _my = _m >> GSH;                            \
  if (_my > 0)    { int _c = c1[_m - GWD]; if (_c != (cid)) { ++CNT; ADD16(P, xp + (i64)_c * 16); } } \
  if (_mx > 0)    { int _c = c1[_m - 1];   if (_c != (cid)) { ++CNT; ADD16(P, xp + (i64)_c * 16); } } \
  if (_mx < GMSK) { int _c = c1[_m + 1];   if (_c != (cid)) { ++CNT; ADD16(P, xp + (i64)_c * 16); } } \
  if (_my < GMSK) { int _c = c1[_m + GWD]; if (_c != (cid)) { ++CNT; ADD16(P, xp + (i64)_c * 16); } } \
} while(0)

__global__ __launch_bounds__(256)
void kE12_conv2_reduce(const int* __restrict__ mem1, const int* __restrict__ c1,
                       const float* __restrict__ xp,
                       const float* __restrict__ W2T, const float* __restrict__ W2rT,
                       const float* __restrict__ b2,
                       const int2* __restrict__ Ldesc, const int* __restrict__ countBuf,
                       float* __restrict__ partials) {
  __shared__ float red[128][33];   // 16.9 KB
  int count = *countBuf;
  int nActive = (2 * count + 255) >> 8;
  int b = blockIdx.x;
  if (b >= nActive) {
    if (threadIdx.x < 33) partials[(i64)threadIdx.x * gridDim.x + b] = 0.f;
    return;
  }
  int xcd = b & 7, idx = b >> 3;
  int q = nActive >> 3, r = nActive & 7;
  int w = (xcd < r ? xcd * (q + 1) : r * (q + 1) + (xcd - r) * q) + idx;

  int gt = w * 256 + threadIdx.x;
  int pi = gt >> 1;
  int which = gt & 1;
  int pairIdx = threadIdx.x >> 1;
  bool active = pi < count;
  bool doconv = false;
  DECL16(s); DECL16(hh); int cnt = 0;
  if (active) {
    int2 dsc = Ldesc[pi];
    int myhead = which ? dsc.y : dsc.x;
    doconv = (which == 0) || (dsc.y != dsc.x);
    if (doconv) {
      int pm = mem1[myhead];
      bool mm = (pm != myhead);
      GATHER_MEMBER(s, cnt, myhead, myhead);
      if (mm) GATHER_MEMBER(s, cnt, pm, myhead);
      LOAD16(hh, xp + (i64)myhead * 16);
    }
  }
  float cf = (float)(cnt > 1 ? cnt : 1);
  float inv = 1.0f / cf;
  MUL16(s, inv);

  bool evenLane = (which == 0);

  for (int f = 0; f < 32; ++f) {
    const float4* wc = (const float4*)(W2T + (f << 4));
    float4 c0 = wc[0], c1v = wc[1], c2 = wc[2], c3 = wc[3];
    const float4* wr = (const float4*)(W2rT + (f << 4));
    float4 r0 = wr[0], r1 = wr[1], r2 = wr[2], r3 = wr[3];
    float bf = b2[f];
    float val = 0.f;
    if (doconv) {
      // 4 independent 8-term chains -> 4x ILP on the FMA dependency chain
      float a0 = s0 * c0.x + s1 * c0.y + s2 * c0.z + s3 * c0.w
               + hh0 * r0.x + hh1 * r0.y + hh2 * r0.z + hh3 * r0.w;
      float a1 = s4 * c1v.x + s5 * c1v.y + s6 * c1v.z + s7 * c1v.w
               + hh4 * r1.x + hh5 * r1.y + hh6 * r1.z + hh7 * r1.w;
      float a2 = s8 * c2.x + s9 * c2.y + s10 * c2.z + s11 * c2.w
               + hh8 * r2.x + hh9 * r2.y + hh10 * r2.z + hh11 * r2.w;
      float a3 = s12 * c3.x + s13 * c3.y + s14 * c3.z + s15 * c3.w
               + hh12 * r3.x + hh13 * r3.y + hh14 * r3.z + hh15 * r3.w;
      float a = ((a0 + a1) + (a2 + a3)) + bf;
      val = fmaxf(a, 0.0f);
    }
    float pmx = fmaxf(val, __shfl_xor(val, 1, 64));
    if (evenLane) red[pairIdx][f] = pmx;
  }
  if (evenLane) red[pairIdx][32] = active ? 1.f : 0.f;
  __syncthreads();
  if (threadIdx.x < 33) {
    int t = threadIdx.x;
    float ssum = 0.f;
    for (int rr = 0; rr < 128; ++rr) ssum += red[rr][t];
    partials[(i64)t * gridDim.x + b] = ssum;
  }
}

// ============ F: fused final reduce (33 x NB) + tiny MLP head ============
__global__ __launch_bounds__(256)
void kF_final(const float* __restrict__ partials, int NB,
              const float* __restrict__ lin1w, const float* __restrict__ lin1b,
              const float* __restrict__ lin2w, const float* __restrict__ lin2b,
              float* __restrict__ out) {
  __shared__ float sm[33][8];
  __shared__ float tot[33];
  int t = threadIdx.x;
  int chunk = NB / 8;
  for (int idx = t; idx < 33 * 8; idx += 256) {
    int r = idx >> 3, pp = idx & 7;
    const float* p = partials + (i64)r * NB + (i64)pp * chunk;
    float a = 0.f;
    for (int k = 0; k < chunk; ++k) a += p[k];
    sm[r][pp] = a;
  }
  __syncthreads();
  if (t < 33) {
    tot[t] = ((sm[t][0] + sm[t][1]) + (sm[t][2] + sm[t][3]))
           + ((sm[t][4] + sm[t][5]) + (sm[t][6] + sm[t][7]));
  }
  __syncthreads();
  if (t == 0) {
    float cnt = tot[32];
    float pooled[32];
#pragma unroll
    for (int f = 0; f < 32; ++f) pooled[f] = tot[f] / cnt;
    float h[8];
#pragma unroll
    for (int j = 0; j < 8; ++j) {
      float a = 0.f;
#pragma unroll
      for (int k = 0; k < 32; ++k) a += pooled[k] * lin1w[k * 8 + j];
      a += lin1b[j];
      h[j] = a >= 0.f ? a : 0.1f * a;
    }
#pragma unroll
    for (int m = 0; m < 2; ++m) {
      float a = 0.f;
#pragma unroll
      for (int j = 0; j < 8; ++j) a += h[j] * lin2w[j * 2 + m];
      out[m] = a + lin2b[m];
    }
  }
}

extern "C" void kernel_launch(void* const* d_in, const int* in_sizes, int n_in,
                              void* d_out, int out_size, void* d_ws, size_t ws_size,
                              hipStream_t stream) {
  const float* x   = (const float*)d_in[0];
  const float* pos = (const float*)d_in[1];
  const float* W1  = (const float*)d_in[3];
  const float* W1r = (const float*)d_in[4];
  const float* b1  = (const float*)d_in[5];
  const float* W2  = (const float*)d_in[6];
  const float* W2r = (const float*)d_in[7];
  const float* b2  = (const float*)d_in[8];
  const float* l1w = (const float*)d_in[9];
  const float* l1b = (const float*)d_in[10];
  const float* l2w = (const float*)d_in[11];
  const float* l2b = (const float*)d_in[12];
  float* out = (float*)d_out;

  const int n = in_sizes[0] / 5;  // 1048576
  const int B = 256;
  const int gn = (n + B - 1) / B; // 4096
  const int ge = 2 * gn;          // kE12 grid

  float* base = (float*)d_ws;
  i64 off = 0;
  float* xp       = base + off; off += (i64)16 * n;
  float* pd       = base + off; off += (i64)4 * n;
  int*   mem1     = (int*)(base + off); off += n;
  int*   c1       = (int*)(base + off); off += n;
  int*   partner2 = (int*)(base + off); off += n;
  int*   partner1 = (int*)(base + off); off += 2 * n;
  int2*  Ldesc    = (int2*)partner1;
  int*   blkCnt   = (int*)(base + off); off += gn;
  int*   blkOff   = (int*)(base + off); off += gn;
  int*   countBuf = (int*)(base + off); off += 1;
  off = (off + 3) & ~(i64)3;
  float* W2T      = base + off; off += 512;
  float* W2rT     = base + off; off += 512;
  float* partials = base + off; off += (i64)33 * ge;
  (void)ws_size; (void)n_in; (void)out_size;

  kA_match1<<<gn, B, 0, stream>>>(x, partner1, n);
  kB_pool1<<<gn, B, 0, stream>>>(x, pos, partner1, W1, W1r, b1, c1, mem1, xp, pd, n);
  kC_deg2<<<gn, B, 0, stream>>>(mem1, c1, pd, n);
  kD_match2<<<gn, B, 0, stream>>>(mem1, c1, pd, partner2, n);
  kP_count<<<gn, B, 0, stream>>>(c1, partner2, blkCnt, n);
  kP_scan<<<1, 256, 0, stream>>>(blkCnt, blkOff, countBuf, gn, W2, W2r, W2T, W2rT);
  kP_write<<<gn, B, 0, stream>>>(c1, partner2, blkOff, Ldesc, n);
  kE12_conv2_reduce<<<ge, B, 0, stream>>>(mem1, c1, xp, W2T, W2rT, b2,
                                          Ldesc, countBuf, partials);
  kF_final<<<1, 256, 0, stream>>>(partials, ge, l1w, l1b, l2w, l2b, out);
}

// Round 19
// 183.580 us; speedup vs baseline: 2.0510x; 2.0510x over previous
//
#include <hip/hip_runtime.h>
#include <math.h>

typedef long long i64;
typedef unsigned long long u64;

#define GWD 1024
#define GMSK 1023
#define GSH 10

__device__ __forceinline__ int xcd_band(int b, int nb) {
  return (b & 7) * (nb >> 3) + (b >> 3);
}

__device__ __forceinline__ int deg_of(int m) {
  int xx = m & GMSK, yy = m >> GSH;
  return (xx > 0) + (xx < GMSK) + (yy > 0) + (yy < GMSK);
}

// ============ A: level-1 matching, fully static neighbor slots ============
__global__ __launch_bounds__(256)
void kA_match1(const float* __restrict__ x, int* __restrict__ partner1, int n) {
#pragma clang fp contract(off)
  int m = xcd_band(blockIdx.x, gridDim.x) * 256 + threadIdx.x;
  if (m >= n) return;
  int xx = m & GMSK, yy = m >> GSH;
  bool vW = xx > 0, vE = xx < GMSK, vN = yy > 0, vS = yy < GMSK;
  int cnt = (int)vW + (int)vE + (int)vN + (int)vS;
  float invi = 1.0f / (float)cnt;
  float xm0 = x[(i64)m * 5];
  float best = -INFINITY;
  int pr = n;
#define NB1(valid, J)                                                  \
  if (valid) {                                                         \
    int j = (J);                                                       \
    float a0 = x[(i64)j * 5];                                          \
    float w = fabsf(xm0 - a0) * (invi + 1.0f / (float)deg_of(j));      \
    if (w > best) { best = w; pr = j; }                                \
  }
  NB1(vN, m - GWD)
  NB1(vW, m - 1)
  NB1(vE, m + 1)
  NB1(vS, m + GWD)
#undef NB1
  partner1[m] = pr;
}

// ============ B: c1 + mem1 (all nodes) + head-only xp / pd.xy ============
__device__ __forceinline__ void conv1_static(const float* __restrict__ x, int m,
                                             const float* w1, const float* w1r,
                                             const float* b1, float (&out)[16]) {
  int xx = m & GMSK, yy = m >> GSH;
  bool vW = xx > 0, vE = xx < GMSK, vN = yy > 0, vS = yy < GMSK;
  int cnt = (int)vW + (int)vE + (int)vN + (int)vS;
  float s0 = 0.f, s1 = 0.f, s2 = 0.f, s3 = 0.f, s4 = 0.f;
#define ACC1(valid, J)                                     \
  if (valid) {                                             \
    const float* xj = x + (i64)(J) * 5;                    \
    s0 += xj[0]; s1 += xj[1]; s2 += xj[2];                 \
    s3 += xj[3]; s4 += xj[4];                              \
  }
  ACC1(vN, m - GWD)
  ACC1(vW, m - 1)
  ACC1(vE, m + 1)
  ACC1(vS, m + GWD)
#undef ACC1
  const float* xm = x + (i64)m * 5;
  float m0 = xm[0], m1 = xm[1], m2 = xm[2], m3 = xm[3], m4 = xm[4];
  float cf = (float)cnt;
#pragma unroll
  for (int f = 0; f < 16; ++f) {
    float a  = s0 * w1[f] + s1 * w1[16 + f] + s2 * w1[32 + f] + s3 * w1[48 + f] + s4 * w1[64 + f];
    float rt = m0 * w1r[f] + m1 * w1r[16 + f] + m2 * w1r[32 + f] + m3 * w1r[48 + f] + m4 * w1r[64 + f];
    out[f] = fmaxf(a / cf + rt + b1[f], 0.0f);
  }
}

__global__ __launch_bounds__(256)
void kB_pool1(const float* __restrict__ x, const float* __restrict__ pos,
              const int* __restrict__ partner1,
              const float* __restrict__ W1, const float* __restrict__ W1r,
              const float* __restrict__ b1,
              int* __restrict__ c1, int* __restrict__ mem1,
              float* __restrict__ xp, float* __restrict__ pd, int n) {
  __shared__ float w1s[80], w1rs[80], b1s[16];
  for (int t = threadIdx.x; t < 80; t += 256) { w1s[t] = W1[t]; w1rs[t] = W1r[t]; }
  if (threadIdx.x < 16) b1s[threadIdx.x] = b1[threadIdx.x];
  __syncthreads();
  int m = xcd_band(blockIdx.x, gridDim.x) * 256 + threadIdx.x;
  if (m >= n) return;
  int p = partner1[m];
  bool mut = (partner1[p] == m);
  int head = mut ? min(m, p) : m;
  c1[m] = head;
  mem1[m] = mut ? p : m;
  if (head != m) return;

  float px = pos[(i64)m * 2], py = pos[(i64)m * 2 + 1];
  if (mut) {
    px = (px + pos[(i64)p * 2]) * 0.5f;
    py = (py + pos[(i64)p * 2 + 1]) * 0.5f;
  }
  pd[(i64)m * 4]     = px;
  pd[(i64)m * 4 + 1] = py;

  float v[16];
  conv1_static(x, m, w1s, w1rs, b1s, v);
  if (mut) {
    float u[16];
    conv1_static(x, p, w1s, w1rs, b1s, u);
#pragma unroll
    for (int f = 0; f < 16; ++f) v[f] = fmaxf(v[f], u[f]);
  }
#pragma unroll
  for (int f = 0; f < 16; ++f) xp[(i64)m * 16 + f] = v[f];
}

// ============ C: coarse inverse-degree into pd.z (heads only) ============
__device__ __forceinline__ int dcount(const int* __restrict__ c1, int q, int cq) {
  int xx = q & GMSK, yy = q >> GSH;
  int d = 0;
  if (yy > 0    && c1[q - GWD] != cq) ++d;
  if (xx > 0    && c1[q - 1]   != cq) ++d;
  if (xx < GMSK && c1[q + 1]   != cq) ++d;
  if (yy < GMSK && c1[q + GWD] != cq) ++d;
  return d;
}

__global__ __launch_bounds__(256)
void kC_deg2(const int* __restrict__ mem1, const int* __restrict__ c1,
             float* __restrict__ pd, int n) {
  int m = xcd_band(blockIdx.x, gridDim.x) * 256 + threadIdx.x;
  if (m >= n) return;
  if (c1[m] != m) return;
  int p = mem1[m];
  bool mut = (p != m);
  int d = dcount(c1, m, m);
  if (mut) d += dcount(c1, p, m);
  pd[(i64)m * 4 + 2] = (d > 0) ? 1.0f / (float)d : 0.0f;
}

// ============ D: level-2 matching (heads only), packed pd float4 reads ============
__global__ __launch_bounds__(256)
void kD_match2(const int* __restrict__ mem1, const int* __restrict__ c1,
               const float* __restrict__ pd, int* __restrict__ partner2, int n) {
#pragma clang fp contract(off)
  int i = xcd_band(blockIdx.x, gridDim.x) * 256 + threadIdx.x;
  if (i >= n) return;
  if (c1[i] != i) return;
  int p = mem1[i];
  bool mut = (p != i);
  float4 mine = *(const float4*)(pd + (i64)i * 4);
  float pix = mine.x, piy = mine.y, invi = mine.z;
  float best = -INFINITY;
  int bc = n;
#define NB2(valid, J)                                                   \
  if (valid) {                                                          \
    int j = (J);                                                        \
    int cu = c1[j];                                                     \
    if (cu != i) {                                                      \
      float4 u = *(const float4*)(pd + (i64)cu * 4);                    \
      float dx = pix - u.x;                                             \
      float dy = piy - u.y;                                             \
      float attr = sqrtf((dx * dx + dy * dy) + 1e-12f);                 \
      float w = attr * (invi + u.z);                                    \
      if (w > best) { best = w; bc = cu; }                              \
      else if (w == best && cu < bc) bc = cu;                           \
    }                                                                   \
  }
  {
    int xx = i & GMSK, yy = i >> GSH;
    NB2(yy > 0, i - GWD)
    NB2(xx > 0, i - 1)
    NB2(xx < GMSK, i + 1)
    NB2(yy < GMSK, i + GWD)
  }
  if (mut) {
    int qx = p & GMSK, qy = p >> GSH;
    NB2(qy > 0, p - GWD)
    NB2(qx > 0, p - 1)
    NB2(qx < GMSK, p + 1)
    NB2(qy < GMSK, p + GWD)
  }
#undef NB2
  partner2[i] = (bc >= n) ? i : bc;
}

// ============ P: deterministic compaction of level-2 heads -> int2 descriptors ============
__device__ __forceinline__ bool l2head(const int* __restrict__ c1,
                                       const int* __restrict__ partner2, int i, int n) {
  if (i >= n || c1[i] != i) return false;
  int p2 = partner2[i];
  bool mut2 = (p2 != i) && (partner2[p2] == i);
  return !(mut2 && p2 < i);
}

__global__ __launch_bounds__(256)
void kP_count(const int* __restrict__ c1, const int* __restrict__ partner2,
              int* __restrict__ blockCounts, int n) {
  int w = xcd_band(blockIdx.x, gridDim.x);
  int i = w * 256 + threadIdx.x;
  bool a = l2head(c1, partner2, i, n);
  u64 b = __ballot(a);
  __shared__ int wc4[4];
  int lane = threadIdx.x & 63, wv = threadIdx.x >> 6;
  if (lane == 0) wc4[wv] = __popcll(b);
  __syncthreads();
  if (threadIdx.x == 0) blockCounts[w] = wc4[0] + wc4[1] + wc4[2] + wc4[3];
}

__global__ __launch_bounds__(256)
void kP_scan(const int* __restrict__ blockCounts, int* __restrict__ blockOffsets,
             int* __restrict__ countBuf, int nblk,
             const float* __restrict__ W2, const float* __restrict__ W2r,
             float* __restrict__ W2T, float* __restrict__ W2rT) {
  int t = threadIdx.x;
  for (int e = t; e < 512; e += 256) {
    int k = e >> 5, f = e & 31;
    W2T[f * 16 + k]  = W2[e];
    W2rT[f * 16 + k] = W2r[e];
  }
  __shared__ int tsum[256];
  __shared__ int toff[256];
  int per = (nblk + 255) / 256;
  int base = t * per;
  int s = 0;
  for (int k = 0; k < per; ++k) { int q = base + k; if (q < nblk) s += blockCounts[q]; }
  tsum[t] = s;
  __syncthreads();
  if (t == 0) {
    int a = 0;
    for (int k = 0; k < 256; ++k) { toff[k] = a; a += tsum[k]; }
    *countBuf = a;
  }
  __syncthreads();
  int off = toff[t];
  for (int k = 0; k < per; ++k) {
    int q = base + k;
    if (q < nblk) { blockOffsets[q] = off; off += blockCounts[q]; }
  }
}

__global__ __launch_bounds__(256)
void kP_write(const int* __restrict__ c1, const int* __restrict__ partner2,
              const int* __restrict__ blockOffsets, int2* __restrict__ Ldesc, int n) {
  int w = xcd_band(blockIdx.x, gridDim.x);
  int i = w * 256 + threadIdx.x;
  bool a = l2head(c1, partner2, i, n);
  u64 b = __ballot(a);
  int lane = threadIdx.x & 63, wv = threadIdx.x >> 6;
  __shared__ int woff[4];
  if (lane == 0) woff[wv] = __popcll(b);
  __syncthreads();
  int pre = 0;
  for (int k = 0; k < wv; ++k) pre += woff[k];
  int rank = __popcll(b & ((lane == 0) ? 0ull : ((1ull << lane) - 1ull)));
  if (a) {
    int p2 = partner2[i];
    bool mut2 = (p2 != i) && (partner2[p2] == i);
    Ldesc[blockOffsets[w] + pre + rank] = make_int2(i, mut2 ? p2 : i);
  }
}

// ============ E12: conv2 + pool2 — LDS reduction + 4-way ILP feature sums ============
#define DECL16(P) \
  float P##0=0.f,P##1=0.f,P##2=0.f,P##3=0.f,P##4=0.f,P##5=0.f,P##6=0.f,P##7=0.f, \
        P##8=0.f,P##9=0.f,P##10=0.f,P##11=0.f,P##12=0.f,P##13=0.f,P##14=0.f,P##15=0.f

#define LOAD16(P, ptr) do { const float* _q=(ptr); \
  P##0=_q[0]; P##1=_q[1]; P##2=_q[2]; P##3=_q[3]; P##4=_q[4]; P##5=_q[5]; P##6=_q[6]; P##7=_q[7]; \
  P##8=_q[8]; P##9=_q[9]; P##10=_q[10]; P##11=_q[11]; P##12=_q[12]; P##13=_q[13]; P##14=_q[14]; P##15=_q[15]; } while(0)

#define ADD16(P, ptr) do { const float* _q=(ptr); \
  P##0+=_q[0]; P##1+=_q[1]; P##2+=_q[2]; P##3+=_q[3]; P##4+=_q[4]; P##5+=_q[5]; P##6+=_q[6]; P##7+=_q[7]; \
  P##8+=_q[8]; P##9+=_q[9]; P##10+=_q[10]; P##11+=_q[11]; P##12+=_q[12]; P##13+=_q[13]; P##14+=_q[14]; P##15+=_q[15]; } while(0)

#define MUL16(P, v) do { float _v=(v); \
  P##0*=_v; P##1*=_v; P##2*=_v; P##3*=_v; P##4*=_v; P##5*=_v; P##6*=_v; P##7*=_v; \
  P##8*=_v; P##9*=_v; P##10*=_v; P##11*=_v; P##12*=_v; P##13*=_v; P##14*=_v; P##15*=_v; } while(0)

#define GATHER_MEMBER(P, CNT, m, cid) do {                                      \
  int _m = (m); int _mx = _m & GMSK, _my = _m >> GSH;                            \
  if (_my > 0)    { int _c = c1[_m - GWD]; if (_c != (cid)) { ++CNT; ADD16(P, xp + (i64)_c * 16); } } \
  if (_mx > 0)    { int _c = c1[_m - 1];   if (_c != (cid)) { ++CNT; ADD16(P, xp + (i64)_c * 16); } } \
  if (_mx < GMSK) { int _c = c1[_m + 1];   if (_c != (cid)) { ++CNT; ADD16(P, xp + (i64)_c * 16); } } \
  if (_my < GMSK) { int _c = c1[_m + GWD]; if (_c != (cid)) { ++CNT; ADD16(P, xp + (i64)_c * 16); } } \
} while(0)

__global__ __launch_bounds__(256)
void kE12_conv2_reduce(const int* __restrict__ mem1, const int* __restrict__ c1,
                       const float* __restrict__ xp,
                       const float* __restrict__ W2T, const float* __restrict__ W2rT,
                       const float* __restrict__ b2,
                       const int2* __restrict__ Ldesc, const int* __restrict__ countBuf,
                       float* __restrict__ partials) {
  __shared__ float red[128][33];   // 16.9 KB
  int count = *countBuf;
  int nActive = (2 * count + 255) >> 8;
  int b = blockIdx.x;
  if (b >= nActive) {
    if (threadIdx.x < 33) partials[(i64)threadIdx.x * gridDim.x + b] = 0.f;
    return;
  }
  int xcd = b & 7, idx = b >> 3;
  int q = nActive >> 3, r = nActive & 7;
  int w = (xcd < r ? xcd * (q + 1) : r * (q + 1) + (xcd - r) * q) + idx;

  int gt = w * 256 + threadIdx.x;
  int pi = gt >> 1;
  int which = gt & 1;
  int pairIdx = threadIdx.x >> 1;
  bool active = pi < count;
  bool doconv = false;
  DECL16(s); DECL16(hh); int cnt = 0;
  if (active) {
    int2 dsc = Ldesc[pi];
    int myhead = which ? dsc.y : dsc.x;
    doconv = (which == 0) || (dsc.y != dsc.x);
    if (doconv) {
      int pm = mem1[myhead];
      bool mm = (pm != myhead);
      GATHER_MEMBER(s, cnt, myhead, myhead);
      if (mm) GATHER_MEMBER(s, cnt, pm, myhead);
      LOAD16(hh, xp + (i64)myhead * 16);
    }
  }
  float cf = (float)(cnt > 1 ? cnt : 1);
  float inv = 1.0f / cf;
  MUL16(s, inv);

  bool evenLane = (which == 0);

  for (int f = 0; f < 32; ++f) {
    const float4* wc = (const float4*)(W2T + (f << 4));
    float4 c0 = wc[0], c1v = wc[1], c2 = wc[2], c3 = wc[3];
    const float4* wr = (const float4*)(W2rT + (f << 4));
    float4 r0 = wr[0], r1 = wr[1], r2 = wr[2], r3 = wr[3];
    float bf = b2[f];
    float val = 0.f;
    if (doconv) {
      float a0 = s0 * c0.x + s1 * c0.y + s2 * c0.z + s3 * c0.w
               + hh0 * r0.x + hh1 * r0.y + hh2 * r0.z + hh3 * r0.w;
      float a1 = s4 * c1v.x + s5 * c1v.y + s6 * c1v.z + s7 * c1v.w
               + hh4 * r1.x + hh5 * r1.y + hh6 * r1.z + hh7 * r1.w;
      float a2 = s8 * c2.x + s9 * c2.y + s10 * c2.z + s11 * c2.w
               + hh8 * r2.x + hh9 * r2.y + hh10 * r2.z + hh11 * r2.w;
      float a3 = s12 * c3.x + s13 * c3.y + s14 * c3.z + s15 * c3.w
               + hh12 * r3.x + hh13 * r3.y + hh14 * r3.z + hh15 * r3.w;
      float a = ((a0 + a1) + (a2 + a3)) + bf;
      val = fmaxf(a, 0.0f);
    }
    float pmx = fmaxf(val, __shfl_xor(val, 1, 64));
    if (evenLane) red[pairIdx][f] = pmx;
  }
  if (evenLane) red[pairIdx][32] = active ? 1.f : 0.f;
  __syncthreads();
  if (threadIdx.x < 33) {
    int t = threadIdx.x;
    float ssum = 0.f;
    for (int rr = 0; rr < 128; ++rr) ssum += red[rr][t];
    partials[(i64)t * gridDim.x + b] = ssum;
  }
}

// ============ F1: parallel row reduction of partials[33][NB] ============
__global__ __launch_bounds__(256)
void kF1_rowsum(const float* __restrict__ partials, int NB, float* __restrict__ tot) {
  int r = blockIdx.x;  // 0..32
  const float* p = partials + (i64)r * NB;
  float a = 0.f;
  for (int k = threadIdx.x; k < NB; k += 256) a += p[k];
  __shared__ float sm[256];
  sm[threadIdx.x] = a;
  __syncthreads();
  for (int s = 128; s > 0; s >>= 1) {
    if (threadIdx.x < s) sm[threadIdx.x] += sm[threadIdx.x + s];
    __syncthreads();
  }
  if (threadIdx.x == 0) tot[r] = sm[0];
}

// ============ F2: tiny MLP head ============
__global__ __launch_bounds__(64)
void kF2_mlp(const float* __restrict__ tot,
             const float* __restrict__ lin1w, const float* __restrict__ lin1b,
             const float* __restrict__ lin2w, const float* __restrict__ lin2b,
             float* __restrict__ out) {
  if (threadIdx.x != 0) return;
  float cnt = tot[32];
  float pooled[32];
#pragma unroll
  for (int f = 0; f < 32; ++f) pooled[f] = tot[f] / cnt;
  float h[8];
#pragma unroll
  for (int j = 0; j < 8; ++j) {
    float a = 0.f;
#pragma unroll
    for (int k = 0; k < 32; ++k) a += pooled[k] * lin1w[k * 8 + j];
    a += lin1b[j];
    h[j] = a >= 0.f ? a : 0.1f * a;
  }
#pragma unroll
  for (int m = 0; m < 2; ++m) {
    float a = 0.f;
#pragma unroll
    for (int j = 0; j < 8; ++j) a += h[j] * lin2w[j * 2 + m];
    out[m] = a + lin2b[m];
  }
}

extern "C" void kernel_launch(void* const* d_in, const int* in_sizes, int n_in,
                              void* d_out, int out_size, void* d_ws, size_t ws_size,
                              hipStream_t stream) {
  const float* x   = (const float*)d_in[0];
  const float* pos = (const float*)d_in[1];
  const float* W1  = (const float*)d_in[3];
  const float* W1r = (const float*)d_in[4];
  const float* b1  = (const float*)d_in[5];
  const float* W2  = (const float*)d_in[6];
  const float* W2r = (const float*)d_in[7];
  const float* b2  = (const float*)d_in[8];
  const float* l1w = (const float*)d_in[9];
  const float* l1b = (const float*)d_in[10];
  const float* l2w = (const float*)d_in[11];
  const float* l2b = (const float*)d_in[12];
  float* out = (float*)d_out;

  const int n = in_sizes[0] / 5;  // 1048576
  const int B = 256;
  const int gn = (n + B - 1) / B; // 4096
  const int ge = 2 * gn;          // kE12 grid

  float* base = (float*)d_ws;
  i64 off = 0;
  float* xp       = base + off; off += (i64)16 * n;
  float* pd       = base + off; off += (i64)4 * n;
  int*   mem1     = (int*)(base + off); off += n;
  int*   c1       = (int*)(base + off); off += n;
  int*   partner2 = (int*)(base + off); off += n;
  int*   partner1 = (int*)(base + off); off += 2 * n;
  int2*  Ldesc    = (int2*)partner1;
  int*   blkCnt   = (int*)(base + off); off += gn;
  int*   blkOff   = (int*)(base + off); off += gn;
  int*   countBuf = (int*)(base + off); off += 1;
  off = (off + 3) & ~(i64)3;
  float* W2T      = base + off; off += 512;
  float* W2rT     = base + off; off += 512;
  float* partials = base + off; off += (i64)33 * ge;
  float* tot      = base + off; off += 33;
  (void)ws_size; (void)n_in; (void)out_size;

  kA_match1<<<gn, B, 0, stream>>>(x, partner1, n);
  kB_pool1<<<gn, B, 0, stream>>>(x, pos, partner1, W1, W1r, b1, c1, mem1, xp, pd, n);
  kC_deg2<<<gn, B, 0, stream>>>(mem1, c1, pd, n);
  kD_match2<<<gn, B, 0, stream>>>(mem1, c1, pd, partner2, n);
  kP_count<<<gn, B, 0, stream>>>(c1, partner2, blkCnt, n);
  kP_scan<<<1, 256, 0, stream>>>(blkCnt, blkOff, countBuf, gn, W2, W2r, W2T, W2rT);
  kP_write<<<gn, B, 0, stream>>>(c1, partner2, blkOff, Ldesc, n);
  kE12_conv2_reduce<<<ge, B, 0, stream>>>(mem1, c1, xp, W2T, W2rT, b2,
                                          Ldesc, countBuf, partials);
  kF1_rowsum<<<33, 256, 0, stream>>>(partials, ge, tot);
  kF2_mlp<<<1, 64, 0, stream>>>(tot, l1w, l1b, l2w, l2b, out);
}